// Round 1
// baseline (447.315 us; speedup 1.0000x reference)
//
#include <hip/hip_runtime.h>

// VQ-VAE forward on MI355X, fp32 (no fp32 MFMA on CDNA4 -> vector ALU).
// N = 65536 rows, IN_DIM=256, D=64, K=512.
//
// ws layout (bytes):
//   z:      float[65536*64]  @ 0          (16 MiB)
//   idx:    int[65536]       @ 16777216   (256 KiB)
//   cr:     float[512*256]   @ 17039360   (512 KiB)  = codebook @ dec_w
//   sse:    double           @ 17563648
//   counts: int[512]         @ 17563656
//
// v2 round theory: k_assign/k_encode were LDS-return-path bound (broadcast
// ds_read_b128 = full 12-cyc wave cost even for 16B of unique data -> 4 B of
// LDS traffic per FMA-lane ~= 160 us floor).  Restructure both so the row
// operand comes from wave-uniform global_load (1 L1 transaction, vmcnt path)
// and only the column operand comes from LDS (contiguous, conflict-free).
// All fmaf chain orders preserved bit-exactly -> idx/argmin unchanged.

__device__ __forceinline__ unsigned ford(float s) {
    // order-preserving map float -> unsigned (total order, matches < on floats)
    unsigned b = __float_as_uint(s);
    return (b & 0x80000000u) ? ~b : (b | 0x80000000u);
}

__device__ __forceinline__ void gl_lds16(const float4* g, float4* l) {
    __builtin_amdgcn_global_load_lds((const __attribute__((address_space(1))) char*)g,
                                     (__attribute__((address_space(3))) char*)l, 16, 0, 0);
}

// ---------------- K1: z = x @ enc_w  ([65536,256]x[256,64]) ----------------
// 512 blocks x 512 threads; block = 128 rows, wave = 16 rows, lane = 1 d-col.
// enc_w (64 KB) staged in LDS once; x read via wave-uniform float4 loads
// (all-lanes-same-address -> one L1/L2 transaction, x streamed exactly once).
// Per k4: 4 conflict-free ds_read_b32 (stride 4B over lanes) + 16 uniform x
// loads + 64 FMA -> VALU/HBM bound instead of LDS bound.
// Chain: acc = fmaf(x.w,w3,fmaf(x.z,w2,fmaf(x.y,w1,fmaf(x.x,w0,acc)))) over
// k4 ascending 0..63 -> bit-identical z to previous passing kernel.
__global__ __launch_bounds__(512) void k_encode(const float* __restrict__ x,
                                                const float* __restrict__ enc_w,
                                                float* __restrict__ z) {
    __shared__ float wEs[256 * 64];  // [k][d], 64 KB

    int t = threadIdx.x;
    int d = t & 63, wg = t >> 6;
    size_t row0 = (size_t)blockIdx.x * 128 + (size_t)wg * 16;

    const float4* w4 = (const float4*)enc_w;  // 4096 f4
    float4* wEs4 = (float4*)wEs;
#pragma unroll
    for (int j = 0; j < 8; ++j) gl_lds16(w4 + t + 512 * j, wEs4 + t + 512 * j);

    float acc[16];
#pragma unroll
    for (int r = 0; r < 16; ++r) acc[r] = 0.f;

    const float4* x4 = (const float4*)x + row0 * 64;  // x row = 64 f4
    __syncthreads();

#pragma unroll 2
    for (int k4 = 0; k4 < 64; ++k4) {
        float w0 = wEs[(k4 * 4 + 0) * 64 + d];  // lanes stride 4B: conflict-free
        float w1 = wEs[(k4 * 4 + 1) * 64 + d];
        float w2 = wEs[(k4 * 4 + 2) * 64 + d];
        float w3 = wEs[(k4 * 4 + 3) * 64 + d];
#pragma unroll
        for (int r = 0; r < 16; ++r) {
            float4 xv = x4[(size_t)r * 64 + k4];  // wave-uniform addr -> 1 txn
            acc[r] = fmaf(xv.w, w3, fmaf(xv.z, w2, fmaf(xv.y, w1, fmaf(xv.x, w0, acc[r]))));
        }
    }
#pragma unroll
    for (int r = 0; r < 16; ++r)
        z[(row0 + r) * 64 + d] = acc[r];  // coalesced over d
}

// ---------------- K2: nearest-code assignment + loss/hist ----------------
// 2048 blocks x 256 threads; block = 32 rows, wave = 8 rows (rowgrp=t>>6),
// lane owns 2 codes per 128-code chunk (4 chunks).  z operand via
// wave-uniform global float4 loads (8 rows x 256 B L1-resident); codebook
// chunk transposed into es[k][c] so e-reads are contiguous ds_read_b64.
// Per k4: 8 uniform z loads + 4 b64 LDS + 64 FMA -> VALU-bound.
// NUMERICS UNCHANGED: d0..d3 chains over ascending k, s=(zz+ee)-2f*dot,
// key=(ford(s)<<32)|code minimized -> bit-identical argmin to previous kernel.
__global__ __launch_bounds__(256) void k_assign(const float* __restrict__ z,
                                                const float* __restrict__ cb,
                                                int* __restrict__ idx,
                                                double* __restrict__ sse,
                                                int* __restrict__ counts) {
    __shared__ float es[64 * 128];  // [k][c] current 128-code chunk, 32 KB
    __shared__ float ees[512];      // ||e||^2 per code
    __shared__ float zzs[32];       // ||z||^2 per row
    __shared__ int bestk[32];
    __shared__ int hist[512];

    int t = threadIdx.x;
    int row0 = blockIdx.x * 32;
    int lane = t & 63, wg = t >> 6;
    int cg2 = lane * 2;  // 2 codes per lane within chunk

    const float4* cb4 = (const float4*)cb;

    hist[t] = 0;
    hist[t + 256] = 0;

    // ee per code (same 4-chain order as reference-matching original)
    for (int c = t; c < 512; c += 256) {
        float n0 = 0, n1 = 0, n2 = 0, n3 = 0;
#pragma unroll
        for (int j = 0; j < 16; ++j) {
            float4 e = cb4[c * 16 + j];
            n0 = fmaf(e.x, e.x, n0);
            n1 = fmaf(e.y, e.y, n1);
            n2 = fmaf(e.z, e.z, n2);
            n3 = fmaf(e.w, e.w, n3);
        }
        ees[c] = (n0 + n1) + (n2 + n3);
    }
    // zz per row (same 4-chain order)
    if (t < 32) {
        const float4* zr = (const float4*)z + (size_t)(row0 + t) * 16;
        float a0 = 0, a1 = 0, a2 = 0, a3 = 0;
#pragma unroll
        for (int j = 0; j < 16; ++j) {
            float4 zv = zr[j];
            a0 = fmaf(zv.x, zv.x, a0);
            a1 = fmaf(zv.y, zv.y, a1);
            a2 = fmaf(zv.z, zv.z, a2);
            a3 = fmaf(zv.w, zv.w, a3);
        }
        zzs[t] = (a0 + a1) + (a2 + a3);
    }

    const float4* zw4 = (const float4*)z + (size_t)(row0 + wg * 8) * 16;  // wave's 8 rows
    unsigned long long best[8];
#pragma unroll
    for (int r = 0; r < 8; ++r) best[r] = ~0ull;

    for (int ch = 0; ch < 4; ++ch) {
        __syncthreads();  // prior chunk's es readers done (also covers preamble)
        {
            // stage es[k][c]: transpose-on-write, lanes write stride-4B -> conflict-free
            int cc = t & 127, kq = t >> 7;
            const float4* src = cb4 + (size_t)(ch * 128 + cc) * 16 + kq * 8;
#pragma unroll
            for (int j = 0; j < 8; ++j) {
                float4 v = src[j];
                int k4s = kq * 8 + j;
                es[(k4s * 4 + 0) * 128 + cc] = v.x;
                es[(k4s * 4 + 1) * 128 + cc] = v.y;
                es[(k4s * 4 + 2) * 128 + cc] = v.z;
                es[(k4s * 4 + 3) * 128 + cc] = v.w;
            }
        }
        __syncthreads();

        float d0[8][2], d1[8][2], d2[8][2], d3[8][2];
#pragma unroll
        for (int r = 0; r < 8; ++r) {
            d0[r][0] = d0[r][1] = 0.f;
            d1[r][0] = d1[r][1] = 0.f;
            d2[r][0] = d2[r][1] = 0.f;
            d3[r][0] = d3[r][1] = 0.f;
        }

#pragma unroll 2
        for (int k4 = 0; k4 < 16; ++k4) {
            // contiguous b64 across lanes (512 B span): conflict-free
            float2 e0 = *(const float2*)&es[(k4 * 4 + 0) * 128 + cg2];
            float2 e1 = *(const float2*)&es[(k4 * 4 + 1) * 128 + cg2];
            float2 e2 = *(const float2*)&es[(k4 * 4 + 2) * 128 + cg2];
            float2 e3 = *(const float2*)&es[(k4 * 4 + 3) * 128 + cg2];
#pragma unroll
            for (int r = 0; r < 8; ++r) {
                float4 zv = zw4[r * 16 + k4];  // wave-uniform addr, L1-resident
                d0[r][0] = fmaf(zv.x, e0.x, d0[r][0]);
                d0[r][1] = fmaf(zv.x, e0.y, d0[r][1]);
                d1[r][0] = fmaf(zv.y, e1.x, d1[r][0]);
                d1[r][1] = fmaf(zv.y, e1.y, d1[r][1]);
                d2[r][0] = fmaf(zv.z, e2.x, d2[r][0]);
                d2[r][1] = fmaf(zv.z, e2.y, d2[r][1]);
                d3[r][0] = fmaf(zv.w, e3.x, d3[r][0]);
                d3[r][1] = fmaf(zv.w, e3.y, d3[r][1]);
            }
        }

        float2 eev = *(const float2*)&ees[ch * 128 + cg2];
#pragma unroll
        for (int r = 0; r < 8; ++r) {
            float zz = zzs[wg * 8 + r];
            float dotA = (d0[r][0] + d1[r][0]) + (d2[r][0] + d3[r][0]);
            float dotB = (d0[r][1] + d1[r][1]) + (d2[r][1] + d3[r][1]);
            float sA = (zz + eev.x) - 2.0f * dotA;  // reference-matching fp32 rounding
            float sB = (zz + eev.y) - 2.0f * dotB;
            unsigned long long kA =
                ((unsigned long long)ford(sA) << 32) | (unsigned)(ch * 128 + cg2);
            unsigned long long kB =
                ((unsigned long long)ford(sB) << 32) | (unsigned)(ch * 128 + cg2 + 1);
            if (kA < best[r]) best[r] = kA;
            if (kB < best[r]) best[r] = kB;
        }
    }

    // full-wave key-min per row (ties -> lowest code via key low bits)
#pragma unroll
    for (int r = 0; r < 8; ++r) {
        unsigned long long b = best[r];
#pragma unroll
        for (int off = 1; off <= 32; off <<= 1) {
            unsigned long long o = __shfl_xor(b, off);
            b = o < b ? o : b;
        }
        if (lane == 0) bestk[wg * 8 + r] = (int)(b & 0xffffffffu);
    }
    __syncthreads();

    if (t < 64) {
        double acc = 0.0;
        if (t < 32) {
            int kb = bestk[t];
            idx[row0 + t] = kb;
            atomicAdd(&hist[kb], 1);
            const float4* zr = (const float4*)z + (size_t)(row0 + t) * 16;
#pragma unroll
            for (int j = 0; j < 16; ++j) {
                float4 qv = cb4[kb * 16 + j];
                float4 zv = zr[j];
                float fx = qv.x - zv.x, fy = qv.y - zv.y, fz = qv.z - zv.z, fw = qv.w - zv.w;
                acc += (double)fx * fx + (double)fy * fy + (double)fz * fz + (double)fw * fw;
            }
        }
#pragma unroll
        for (int off = 32; off >= 1; off >>= 1) acc += __shfl_down(acc, off);
        if (t == 0) atomicAdd(sse, acc);
    }
    __syncthreads();
    if (hist[t]) atomicAdd(&counts[t], hist[t]);
    if (hist[t + 256]) atomicAdd(&counts[t + 256], hist[t + 256]);
}

// ---------------- K3a: cr = codebook @ dec_w  ([512,64]x[64,256]) ----------------
// 16 blocks x 256 threads; block does 32 codes; dec_w in LDS. (unchanged)
__global__ __launch_bounds__(256) void k_coderecon(const float* __restrict__ cb,
                                                   const float* __restrict__ dec_w,
                                                   float* __restrict__ cr) {
    __shared__ float wD[64 * 256];  // 64 KB
    __shared__ float qs[32 * 64];   // 8 KB

    int t = threadIdx.x;
    int r0 = blockIdx.x * 32;
    const float4* dw4 = (const float4*)dec_w;
    float4* wD4 = (float4*)wD;
#pragma unroll
    for (int j = 0; j < 16; ++j) wD4[t + 256 * j] = dw4[t + 256 * j];
    {
        const float4* cb4 = (const float4*)cb;
        float4* qs4 = (float4*)qs;
#pragma unroll
        for (int j = 0; j < 2; ++j) qs4[t + 256 * j] = cb4[r0 * 16 + t + 256 * j];
    }
    __syncthreads();

    int l = t & 63, w = t >> 6;  // wave w -> codes w*8..w*8+7; lane -> 4 columns
    float4 acc[8];
#pragma unroll
    for (int j = 0; j < 8; ++j) acc[j] = make_float4(0.f, 0.f, 0.f, 0.f);

    for (int d = 0; d < 64; ++d) {
        float4 wv = wD4[d * 64 + l];
#pragma unroll
        for (int j = 0; j < 8; ++j) {
            float q = qs[(w * 8 + j) * 64 + d];  // broadcast
            acc[j].x = fmaf(q, wv.x, acc[j].x);
            acc[j].y = fmaf(q, wv.y, acc[j].y);
            acc[j].z = fmaf(q, wv.z, acc[j].z);
            acc[j].w = fmaf(q, wv.w, acc[j].w);
        }
    }
    float4* cr4 = (float4*)cr;
#pragma unroll
    for (int j = 0; j < 8; ++j) cr4[(size_t)(r0 + w * 8 + j) * 64 + l] = acc[j];
}

// ---------------- K3b: x_recon[row] = cr[idx[row]] (pure gather) ----------------
// v2: wave-per-row layout.  Lane l handles columns {l, l+64, l+128, l+192}:
// loads and the 4B-aligned stores are 256 B contiguous per wave instruction
// (old layout scattered single dwords at 64 B lane-stride).
__global__ __launch_bounds__(256) void k_gather(const float* __restrict__ cr,
                                                const int* __restrict__ idx,
                                                float* __restrict__ out) {
    int t = threadIdx.x;
    int l = t & 63, w = t >> 6;
    int rowb = blockIdx.x * 16 + w * 4;
#pragma unroll
    for (int i = 0; i < 4; ++i) {
        int row = rowb + i;
        int k = idx[row];  // wave-uniform
        const float* crr = cr + (size_t)k * 256 + l;
        float* o = out + (size_t)row * 256 + l;
#pragma unroll
        for (int j = 0; j < 4; ++j) o[64 * j] = crr[64 * j];
    }
}

// ---------------- K4: loss + perplexity scalars ----------------
__global__ __launch_bounds__(512) void k_final(const double* __restrict__ sse,
                                               const int* __restrict__ counts,
                                               float* __restrict__ out_loss,
                                               float* __restrict__ out_pp) {
    __shared__ double red[8];
    int t = threadIdx.x;
    double p = (double)counts[t] / 65536.0;
    double term = p * log(p + 1e-10);
#pragma unroll
    for (int off = 32; off >= 1; off >>= 1) term += __shfl_down(term, off);
    if ((t & 63) == 0) red[t >> 6] = term;
    __syncthreads();
    if (t == 0) {
        double s = 0;
#pragma unroll
        for (int w = 0; w < 8; ++w) s += red[w];
        out_pp[0] = (float)exp(-s);
        out_loss[0] = (float)(1.25 * sse[0] / 4194304.0);  // (1+0.25)*mean((q-z)^2)
    }
}

extern "C" void kernel_launch(void* const* d_in, const int* in_sizes, int n_in,
                              void* d_out, int out_size, void* d_ws, size_t ws_size,
                              hipStream_t stream) {
    const float* x = (const float*)d_in[0];
    const float* enc_w = (const float*)d_in[1];
    const float* dec_w = (const float*)d_in[2];
    const float* cb = (const float*)d_in[3];
    float* out = (float*)d_out;

    char* ws = (char*)d_ws;
    float* z = (float*)ws;                        // 16 MiB
    int* idx = (int*)(ws + 16777216);             // 256 KiB
    float* cr = (float*)(ws + 17039360);          // 512 KiB
    double* sse = (double*)(ws + 17563648);       // 8 B
    int* counts = (int*)(ws + 17563656);          // 2 KiB

    // ws is poisoned to 0xAA before each launch -> zero the accumulators
    hipMemsetAsync(ws + 17563648, 0, 8 + 2048, stream);

    k_coderecon<<<dim3(16), dim3(256), 0, stream>>>(cb, dec_w, cr);
    k_encode<<<dim3(512), dim3(512), 0, stream>>>(x, enc_w, z);
    k_assign<<<dim3(2048), dim3(256), 0, stream>>>(z, cb, idx, sse, counts);
    k_gather<<<dim3(4096), dim3(256), 0, stream>>>(cr, idx, out + 1);
    k_final<<<dim3(1), dim3(512), 0, stream>>>(sse, counts, out, out + 16777217);
}

// Round 2
// 288.493 us; speedup vs baseline: 1.5505x; 1.5505x over previous
//
#include <hip/hip_runtime.h>

// VQ-VAE forward on MI355X, fp32 (no fp32 MFMA on CDNA4 -> vector ALU).
// N = 65536 rows, IN_DIM=256, D=64, K=512.
//
// ws layout (bytes):
//   z:      float[65536*64]        @ 0          (16 MiB)
//   part:   ull[65536]             @ 16777216   (512 KiB)  argmin keys
//   cr:     float[512*256]         @ 17301504   (512 KiB)  = codebook @ dec_w
//   counts: int[512]               @ 17825792   (2 KiB)
//   spart:  double[2048]           @ 17827840   (16 KiB)   per-block sse partials
//
// v3: k_assign restructured: lane owns 2 z-rows PINNED in VGPRs (asm pin --
// round-0 counters showed VGPR_Count=52 < the 64-reg codebook array, i.e. the
// compiler was rematerializing operands from global every row).  Codes stream
// from LDS as broadcasts: 17 LDS instrs feed 128 FMAs (v1: 16 LDS + 16 VMEM
// per 64 FMAs).  No per-row cross-lane reduce: per-lane best key + one
// u64 atomicMin per row.  Codes split in 4 quarters across blocks for
// occupancy.  k_encode reverted to the proven v1.  Tail fused into k_finish.

__device__ __forceinline__ unsigned ford(float s) {
    // order-preserving map float -> unsigned (total order, matches < on floats)
    unsigned b = __float_as_uint(s);
    return (b & 0x80000000u) ? ~b : (b | 0x80000000u);
}

__device__ __forceinline__ void gl_lds16(const float4* g, float4* l) {
    __builtin_amdgcn_global_load_lds((const __attribute__((address_space(1))) char*)g,
                                     (__attribute__((address_space(3))) char*)l, 16, 0, 0);
}

// ---------------- K1: z = x @ enc_w  ([65536,256]x[256,64]) ----------------
// (v1 verbatim -- proven at baseline)
__global__ __launch_bounds__(512) void k_encode(const float* __restrict__ x,
                                                const float* __restrict__ enc_w,
                                                float* __restrict__ z) {
    __shared__ float4 xs4[128 * 16];  // [row][k4] current chunk, 32 KB
    __shared__ float wEs[64 * 64];    // [k][d] current chunk, 16 KB

    int t = threadIdx.x;
    int row0 = blockIdx.x * 128;
    int d = t & 63, rg = t >> 6;  // 8 waves; wave rg handles rows rg*16..rg*16+15

    const float4* xg = (const float4*)x;      // x row = 64 float4
    const float4* wg = (const float4*)enc_w;  // 4096 float4 total
    float4* wEs4 = (float4*)wEs;

    float acc[16];
#pragma unroll
    for (int r = 0; r < 16; ++r) acc[r] = 0.f;

    for (int c = 0; c < 4; ++c) {
#pragma unroll
        for (int j = 0; j < 4; ++j) {
            int lr = (t >> 4) + 32 * j;
            gl_lds16(xg + (size_t)(row0 + lr) * 64 + c * 16 + (t & 15),
                     xs4 + t + 512 * j);
        }
#pragma unroll
        for (int j = 0; j < 2; ++j)
            gl_lds16(wg + c * 1024 + t + 512 * j, wEs4 + t + 512 * j);
        __syncthreads();

        for (int k4 = 0; k4 < 16; ++k4) {
            float w0 = wEs[(k4 * 4 + 0) * 64 + d];  // 2-way bank alias: free
            float w1 = wEs[(k4 * 4 + 1) * 64 + d];
            float w2 = wEs[(k4 * 4 + 2) * 64 + d];
            float w3 = wEs[(k4 * 4 + 3) * 64 + d];
#pragma unroll
            for (int r = 0; r < 16; ++r) {
                float4 xv = xs4[(rg * 16 + r) * 16 + k4];  // LDS broadcast: free
                acc[r] = fmaf(xv.w, w3, fmaf(xv.z, w2, fmaf(xv.y, w1, fmaf(xv.x, w0, acc[r]))));
            }
        }
        __syncthreads();
    }
#pragma unroll
    for (int r = 0; r < 16; ++r)
        z[(size_t)(row0 + rg * 16 + r) * 64 + d] = acc[r];  // coalesced over d
}

// ---------------- K2: nearest-code assignment ----------------
// grid 512 = quarter-major (bid = q*128 + row_tile) x 256 threads (4 waves).
// Lane owns rows {row0, row0+1} pinned in 128 VGPRs; iterates its quarter's
// 128 codes from LDS broadcast.  Per code per wave: 17 LDS bcast + 128 FMA.
// Per-lane running best key (ford(s)<<32 | code) -> one atomicMin/row.
// NUMERICS: d0..d3 fmaf chains ascending j, s=(zz+ee)-2f*dot, min-key
// tie-break lowest code -> bit-identical argmin to verified versions.
__global__ __launch_bounds__(256, 2) void k_assign(const float* __restrict__ z,
                                                   const float* __restrict__ cb,
                                                   unsigned long long* __restrict__ part) {
    __shared__ float es[128 * 64];  // quarter codebook [c][d], 32 KB
    __shared__ float ees[128];      // ||e||^2 for the quarter

    int t = threadIdx.x, lane = t & 63, wv = t >> 6;
    int q = blockIdx.x >> 7;    // code quarter
    int rt = blockIdx.x & 127;  // row tile
    int c0 = q * 128;
    int row0 = rt * 512 + wv * 128 + lane * 2;  // lane's rows: row0, row0+1

    // stage quarter codebook: 2048 f4 / 256 thr = 8 each (coalesced)
    const float4* cbq = (const float4*)cb + (size_t)c0 * 16;
    float4* es4 = (float4*)es;
#pragma unroll
    for (int j = 0; j < 8; ++j) es4[t + 256 * j] = cbq[t + 256 * j];
    __syncthreads();

    // ee per code (same 4-chain order as verified versions)
    if (t < 128) {
        float n0 = 0, n1 = 0, n2 = 0, n3 = 0;
#pragma unroll
        for (int j = 0; j < 16; ++j) {
            float4 e = es4[t * 16 + j];
            n0 = fmaf(e.x, e.x, n0);
            n1 = fmaf(e.y, e.y, n1);
            n2 = fmaf(e.z, e.z, n2);
            n3 = fmaf(e.w, e.w, n3);
        }
        ees[t] = (n0 + n1) + (n2 + n3);
    }

    // load lane's 2 z-rows into regs and PIN (prevent remat-from-global)
    const float4* zr0 = (const float4*)z + (size_t)row0 * 16;
    float4 zA[16], zB[16];
#pragma unroll
    for (int j = 0; j < 16; ++j) {
        zA[j] = zr0[j];
        zB[j] = zr0[16 + j];
    }
#pragma unroll
    for (int j = 0; j < 16; ++j) {
        asm volatile("" : "+v"(zA[j].x), "+v"(zA[j].y), "+v"(zA[j].z), "+v"(zA[j].w));
        asm volatile("" : "+v"(zB[j].x), "+v"(zB[j].y), "+v"(zB[j].z), "+v"(zB[j].w));
    }

    // zz per row from regs (exact chain)
    float zzA, zzB;
    {
        float a0 = 0, a1 = 0, a2 = 0, a3 = 0;
#pragma unroll
        for (int j = 0; j < 16; ++j) {
            a0 = fmaf(zA[j].x, zA[j].x, a0);
            a1 = fmaf(zA[j].y, zA[j].y, a1);
            a2 = fmaf(zA[j].z, zA[j].z, a2);
            a3 = fmaf(zA[j].w, zA[j].w, a3);
        }
        zzA = (a0 + a1) + (a2 + a3);
        a0 = a1 = a2 = a3 = 0;
#pragma unroll
        for (int j = 0; j < 16; ++j) {
            a0 = fmaf(zB[j].x, zB[j].x, a0);
            a1 = fmaf(zB[j].y, zB[j].y, a1);
            a2 = fmaf(zB[j].z, zB[j].z, a2);
            a3 = fmaf(zB[j].w, zB[j].w, a3);
        }
        zzB = (a0 + a1) + (a2 + a3);
    }
    __syncthreads();

    unsigned long long bestA = ~0ull, bestB = ~0ull;
    for (int c = 0; c < 128; ++c) {
        float d0A = 0, d1A = 0, d2A = 0, d3A = 0;
        float d0B = 0, d1B = 0, d2B = 0, d3B = 0;
#pragma unroll
        for (int j = 0; j < 16; ++j) {
            float4 ev = es4[c * 16 + j];  // LDS broadcast
            d0A = fmaf(zA[j].x, ev.x, d0A);
            d1A = fmaf(zA[j].y, ev.y, d1A);
            d2A = fmaf(zA[j].z, ev.z, d2A);
            d3A = fmaf(zA[j].w, ev.w, d3A);
            d0B = fmaf(zB[j].x, ev.x, d0B);
            d1B = fmaf(zB[j].y, ev.y, d1B);
            d2B = fmaf(zB[j].z, ev.z, d2B);
            d3B = fmaf(zB[j].w, ev.w, d3B);
        }
        float ee = ees[c];
        float dotA = (d0A + d1A) + (d2A + d3A);
        float dotB = (d0B + d1B) + (d2B + d3B);
        float sA = (zzA + ee) - 2.0f * dotA;  // reference-matching fp32 rounding
        float sB = (zzB + ee) - 2.0f * dotB;
        unsigned long long kA = ((unsigned long long)ford(sA) << 32) | (unsigned)(c0 + c);
        unsigned long long kB = ((unsigned long long)ford(sB) << 32) | (unsigned)(c0 + c);
        if (kA < bestA) bestA = kA;
        if (kB < bestB) bestB = kB;
    }
    atomicMin(&part[row0], bestA);
    atomicMin(&part[row0 + 1], bestB);
}

// ---------------- K3a: cr = codebook @ dec_w  ([512,64]x[64,256]) ----------------
// dec_w streamed from L2 per-lane coalesced (drops the 64 KB LDS staging);
// acc chain identical to v1 -> cr bit-identical.
__global__ __launch_bounds__(256) void k_coderecon(const float* __restrict__ cb,
                                                   const float* __restrict__ dec_w,
                                                   float* __restrict__ cr) {
    __shared__ float qs[32 * 64];  // 8 KB

    int t = threadIdx.x;
    int r0 = blockIdx.x * 32;
    {
        const float4* cb4 = (const float4*)cb;
        float4* qs4 = (float4*)qs;
#pragma unroll
        for (int j = 0; j < 2; ++j) qs4[t + 256 * j] = cb4[r0 * 16 + t + 256 * j];
    }
    __syncthreads();

    int l = t & 63, w = t >> 6;  // wave w -> codes w*8..w*8+7; lane -> 4 columns
    const float4* dw4 = (const float4*)dec_w;
    float4 acc[8];
#pragma unroll
    for (int j = 0; j < 8; ++j) acc[j] = make_float4(0.f, 0.f, 0.f, 0.f);

#pragma unroll 4
    for (int d = 0; d < 64; ++d) {
        float4 wv = dw4[d * 64 + l];  // global, coalesced, L2-resident
#pragma unroll
        for (int j = 0; j < 8; ++j) {
            float q = qs[(w * 8 + j) * 64 + d];  // broadcast
            acc[j].x = fmaf(q, wv.x, acc[j].x);
            acc[j].y = fmaf(q, wv.y, acc[j].y);
            acc[j].z = fmaf(q, wv.z, acc[j].z);
            acc[j].w = fmaf(q, wv.w, acc[j].w);
        }
    }
    float4* cr4 = (float4*)cr;
#pragma unroll
    for (int j = 0; j < 8; ++j) cr4[(size_t)(r0 + w * 8 + j) * 64 + l] = acc[j];
}

// ---------------- K3b: fused finish: gather + sse + counts ----------------
// 2048 blocks x 256 thr; wave = 8 rows.  Keys pre-loaded (8-way dup load,
// shfl broadcast).  Stores: lane l writes out1[row*256 + l + 64j] -> 256 B
// contiguous dword segments (out is 4B-aligned only).  sse: lane-private
// double partial (d = lane), one wave reduce per block -> spart[block].
__global__ __launch_bounds__(256) void k_finish(const unsigned long long* __restrict__ part,
                                                const float* __restrict__ z,
                                                const float* __restrict__ cb,
                                                const float* __restrict__ cr,
                                                float* __restrict__ out1,
                                                double* __restrict__ spart,
                                                int* __restrict__ counts) {
    __shared__ double red[4];
    int t = threadIdx.x, l = t & 63, w = t >> 6;
    int row0 = blockIdx.x * 32 + w * 8;

    unsigned long long myk = part[row0 + (l & 7)];  // 8 keys, 8-way duplicated
    double acc = 0.0;
#pragma unroll
    for (int i = 0; i < 8; ++i) {
        int row = row0 + i;
        int kb = (int)(__shfl(myk, i) & 0xffffffffu);
        if (l == 0) atomicAdd(&counts[kb], 1);
        // sse slice: this lane handles dim d = l
        float zv = z[(size_t)row * 64 + l];
        float qv = cb[(size_t)kb * 64 + l];
        float f = qv - zv;
        acc += (double)f * f;
        // reconstruction row copy
        const float* crr = cr + (size_t)kb * 256;
        float* o = out1 + (size_t)row * 256;
#pragma unroll
        for (int j = 0; j < 4; ++j) o[l + 64 * j] = crr[l + 64 * j];
    }
#pragma unroll
    for (int off = 32; off >= 1; off >>= 1) acc += __shfl_down(acc, off);
    if (l == 0) red[w] = acc;
    __syncthreads();
    if (t == 0) spart[blockIdx.x] = (red[0] + red[1]) + (red[2] + red[3]);
}

// ---------------- K4: loss + perplexity scalars ----------------
__global__ __launch_bounds__(512) void k_final(const double* __restrict__ spart,
                                               const int* __restrict__ counts,
                                               float* __restrict__ out_loss,
                                               float* __restrict__ out_pp) {
    __shared__ double redp[8], reds[8];
    int t = threadIdx.x;
    double p = (double)counts[t] / 65536.0;
    double term = p * log(p + 1e-10);
    double s = 0.0;
#pragma unroll
    for (int j = 0; j < 4; ++j) s += spart[t + 512 * j];
#pragma unroll
    for (int off = 32; off >= 1; off >>= 1) {
        term += __shfl_down(term, off);
        s += __shfl_down(s, off);
    }
    if ((t & 63) == 0) {
        redp[t >> 6] = term;
        reds[t >> 6] = s;
    }
    __syncthreads();
    if (t == 0) {
        double st = 0, ss = 0;
#pragma unroll
        for (int w = 0; w < 8; ++w) {
            st += redp[w];
            ss += reds[w];
        }
        out_pp[0] = (float)exp(-st);
        out_loss[0] = (float)(1.25 * ss / 4194304.0);  // (1+0.25)*mean((q-z)^2)
    }
}

extern "C" void kernel_launch(void* const* d_in, const int* in_sizes, int n_in,
                              void* d_out, int out_size, void* d_ws, size_t ws_size,
                              hipStream_t stream) {
    const float* x = (const float*)d_in[0];
    const float* enc_w = (const float*)d_in[1];
    const float* dec_w = (const float*)d_in[2];
    const float* cb = (const float*)d_in[3];
    float* out = (float*)d_out;

    char* ws = (char*)d_ws;
    float* z = (float*)ws;                                       // 16 MiB
    unsigned long long* part = (unsigned long long*)(ws + 16777216);  // 512 KiB
    float* cr = (float*)(ws + 17301504);                         // 512 KiB
    int* counts = (int*)(ws + 17825792);                         // 2 KiB
    double* spart = (double*)(ws + 17827840);                    // 16 KiB

    // ws is poisoned to 0xAA before each launch
    hipMemsetAsync(ws + 16777216, 0xFF, 524288, stream);  // part -> max keys
    hipMemsetAsync(ws + 17825792, 0, 2048, stream);       // counts -> 0

    k_coderecon<<<dim3(16), dim3(256), 0, stream>>>(cb, dec_w, cr);
    k_encode<<<dim3(512), dim3(512), 0, stream>>>(x, enc_w, z);
    k_assign<<<dim3(512), dim3(256), 0, stream>>>(z, cb, part);
    k_finish<<<dim3(2048), dim3(256), 0, stream>>>(part, z, cb, cr, out + 1, spart, counts);
    k_final<<<dim3(1), dim3(512), 0, stream>>>(spart, counts, out, out + 16777217);
}